// Round 4
// baseline (878.588 us; speedup 1.0000x reference)
//
#include <hip/hip_runtime.h>
#include <stdint.h>

#define L48   48
#define NLOC  2304      // 48*48
#define C3CH  256
#define BATCH 4
#define NLOC50 2500     // 50*50 padded grid

typedef _Float16 half8 __attribute__((ext_vector_type(8)));
typedef float    floatx4 __attribute__((ext_vector_type(4)));
typedef unsigned short ushort8v __attribute__((ext_vector_type(8)));

union H16 { _Float16 f; unsigned short u; };

// ---------------- ss: per-location channel sum of squares (fp32) ----------------
__global__ __launch_bounds__(256) void ss_kernel(const float* __restrict__ img,
                                                 float* __restrict__ ss)
{
    int i = blockIdx.x * 256 + threadIdx.x;      // b*NLOC + l
    int b = i / NLOC, l = i - b * NLOC;
    const float* p = img + (size_t)b * C3CH * NLOC + l;
    float a = 0.f;
    #pragma unroll 8
    for (int c = 0; c < C3CH; ++c) { float v = p[c * NLOC]; a += v * v; }
    ss[i] = a;
}

// ---------------- norm: 9-tap sum over zero-padded ss, rsqrt ----------------
__global__ __launch_bounds__(256) void normS_kernel(const float* __restrict__ ss,
                                                    float* __restrict__ inv_norm)
{
    int i = blockIdx.x * 256 + threadIdx.x;
    int b = i / NLOC, l = i - b * NLOC;
    int y = l / L48, x = l - y * L48;
    const float* s = ss + b * NLOC;
    float a = 0.f;
    #pragma unroll
    for (int dy = -1; dy <= 1; ++dy)
        #pragma unroll
        for (int dx = -1; dx <= 1; ++dx) {
            int yy = y + dy, xx = x + dx;
            if ((unsigned)yy < 48u && (unsigned)xx < 48u) a += s[yy * L48 + xx];
        }
    inv_norm[i] = 1.f / fmaxf(sqrtf(a), 1e-12f);
}

// ---------------- prep: fp32 image -> single 50x50-padded channel-last hi/lo planes ----
// plane[b][loc50][c], loc50=(y+1)*50+(x+1); borders pre-zeroed by memset.
__global__ __launch_bounds__(256) void prep_kernel(const float* __restrict__ img,
                                                   unsigned short* __restrict__ hi,
                                                   unsigned short* __restrict__ lo)
{
    __shared__ unsigned short sh[256 * 50];
    __shared__ unsigned short sl[256 * 50];
    int b = blockIdx.x / 48, y = blockIdx.x % 48;
    const float* ib = img + (size_t)b * C3CH * NLOC + y * L48;
    for (int f = threadIdx.x; f < 256 * 48; f += 256) {
        int c = f / 48, x = f - c * 48;
        float v = ib[c * NLOC + x];
        H16 h, l;
        h.f = (_Float16)v;
        l.f = (_Float16)(v - (float)h.f);
        sh[c * 50 + x] = h.u;
        sl[c * 50 + x] = l.u;
    }
    __syncthreads();
    size_t ob = ((size_t)b * NLOC50 + (size_t)(y + 1) * 50 + 1) * 256;
    for (int f = threadIdx.x; f < 48 * 256; f += 256) {
        int x = f >> 8, c = f & 255;
        hi[ob + (size_t)x * 256 + c] = sh[c * 50 + x];
        lo[ob + (size_t)x * 256 + c] = sl[c * 50 + x];
    }
}

// ---------------- search: A direct-from-global (reg prefetch), B via LDS ----------------
// Block 256l x 64m, 4 waves (64x64 each). K chunks of 32 ch; B staged per K=128.
__global__ __launch_bounds__(256, 2) void search_mfma(const unsigned short* __restrict__ Ah_g,
                                                      const unsigned short* __restrict__ Al_g,
                                                      const unsigned short* __restrict__ Bh_g,
                                                      const unsigned short* __restrict__ Bl_g,
                                                      const float* __restrict__ nr_inv,
                                                      unsigned long long* __restrict__ packed)
{
    __shared__ unsigned short lds[2 * 10304];   // Bh [4 sub][64 row][40] pad stride 2576, Bl after
    unsigned short* sBh = lds;
    unsigned short* sBl = lds + 10304;

    const int tid = threadIdx.x, lane = tid & 63, w = tid >> 6;
    const int mrow = lane & 15, quad = lane >> 4, koff = quad * 8;
    const int b = blockIdx.z, l0 = blockIdx.y * 256, m0 = blockIdx.x * 64;

    const _Float16* Ahp = (const _Float16*)(Ah_g + (size_t)b * NLOC50 * 256);
    const _Float16* Alp = (const _Float16*)(Al_g + (size_t)b * NLOC50 * 256);
    const unsigned short* Bhp = Bh_g + (size_t)b * NLOC50 * 256;
    const unsigned short* Blp = Bl_g + (size_t)b * NLOC50 * 256;

    int aoff[4];
    #pragma unroll
    for (int fi = 0; fi < 4; ++fi) {
        int r = l0 + w * 64 + fi * 16 + mrow;
        aoff[fi] = ((r / 48 + 1) * 50 + (r % 48) + 1) * 256 + koff;
    }
    int mloc[4], lofs[4];
    #pragma unroll
    for (int p = 0; p < 4; ++p) {
        int s = p * 256 + tid;
        int mrel = s >> 4, sub = (s >> 2) & 3, g = (s & 3) * 8;
        int m = m0 + mrel;
        mloc[p] = ((m / 48 + 1) * 50 + (m % 48) + 1) * 256 + sub * 32 + g;
        lofs[p] = sub * 2576 + mrel * 40 + g;
    }

    floatx4 acc[4][4];
    #pragma unroll
    for (int i = 0; i < 4; ++i)
        #pragma unroll
        for (int j = 0; j < 4; ++j) acc[i][j] = (floatx4)0.f;

    half8 cAh[4], cAl[4], nAh[4], nAl[4];
    // chunk 0: o=0 (tap -51), ch 0
    #pragma unroll
    for (int fi = 0; fi < 4; ++fi) {
        cAh[fi] = *(const half8*)(Ahp + aoff[fi] - 51 * 256);
        cAl[fi] = *(const half8*)(Alp + aoff[fi] - 51 * 256);
    }

    int q = 0;
    for (int o = 0; o < 9; ++o) {
        const int tap = (o / 3 - 1) * 50 + (o % 3) - 1;
        const int tapB = tap * 256;
        #pragma unroll
        for (int half = 0; half < 2; ++half) {
            __syncthreads();
            const int c0 = half * 128;
            #pragma unroll
            for (int p = 0; p < 4; ++p) {
                int ga = mloc[p] + tapB + c0;
                *(ushort8v*)(sBh + lofs[p]) = *(const ushort8v*)(Bhp + ga);
                *(ushort8v*)(sBl + lofs[p]) = *(const ushort8v*)(Blp + ga);
            }
            __syncthreads();
            #pragma unroll
            for (int sub = 0; sub < 4; ++sub) {
                // prefetch next chunk's A fragments
                int nq = q + 1; if (nq > 71) nq = 71;
                int no = nq >> 3, nch = (nq & 7) * 32;
                int nofs = ((no / 3 - 1) * 50 + (no % 3) - 1) * 256 + nch;
                #pragma unroll
                for (int fi = 0; fi < 4; ++fi) {
                    nAh[fi] = *(const half8*)(Ahp + aoff[fi] + nofs);
                    nAl[fi] = *(const half8*)(Alp + aoff[fi] + nofs);
                }
                const _Float16* bh = (const _Float16*)sBh + sub * 2576 + koff;
                const _Float16* bl = (const _Float16*)sBl + sub * 2576 + koff;
                #pragma unroll
                for (int fj = 0; fj < 4; ++fj) {
                    half8 Bh8 = *(const half8*)(bh + (fj * 16 + mrow) * 40);
                    half8 Bl8 = *(const half8*)(bl + (fj * 16 + mrow) * 40);
                    #pragma unroll
                    for (int fi = 0; fi < 4; ++fi) {
                        acc[fi][fj] = __builtin_amdgcn_mfma_f32_16x16x32_f16(cAh[fi], Bh8, acc[fi][fj], 0, 0, 0);
                        acc[fi][fj] = __builtin_amdgcn_mfma_f32_16x16x32_f16(cAh[fi], Bl8, acc[fi][fj], 0, 0, 0);
                        acc[fi][fj] = __builtin_amdgcn_mfma_f32_16x16x32_f16(cAl[fi], Bh8, acc[fi][fj], 0, 0, 0);
                    }
                }
                #pragma unroll
                for (int fi = 0; fi < 4; ++fi) { cAh[fi] = nAh[fi]; cAl[fi] = nAl[fi]; }
                ++q;
            }
        }
    }

    // ---- epilogue: row-normalize, per-column argmax over 256 l's ----
    __syncthreads();
    float* redv = (float*)lds;               // [16][64]
    int*   redi = (int*)(redv + 1024);

    float bestv[4];
    int   besti[4];
    #pragma unroll
    for (int fj = 0; fj < 4; ++fj) { bestv[fj] = -1e30f; besti[fj] = 0; }

    #pragma unroll
    for (int fi = 0; fi < 4; ++fi) {
        int rowb = l0 + w * 64 + fi * 16 + quad * 4;
        #pragma unroll
        for (int r = 0; r < 4; ++r) {
            float rv = nr_inv[b * NLOC + rowb + r];
            #pragma unroll
            for (int fj = 0; fj < 4; ++fj) {
                float v = acc[fi][fj][r] * rv;
                if (v > bestv[fj]) { bestv[fj] = v; besti[fj] = rowb + r; }
            }
        }
    }
    int cand = w * 4 + quad;   // 0..15
    #pragma unroll
    for (int fj = 0; fj < 4; ++fj) {
        int col = fj * 16 + mrow;
        redv[cand * 64 + col] = bestv[fj];
        redi[cand * 64 + col] = besti[fj];
    }
    __syncthreads();
    if (tid < 64) {
        float best = redv[tid];
        int   bi   = redi[tid];
        #pragma unroll
        for (int c = 1; c < 16; ++c) {
            float v  = redv[c * 64 + tid];
            int   i2 = redi[c * 64 + tid];
            if (v > best || (v == best && i2 < bi)) { best = v; bi = i2; }
        }
        unsigned int sv = __float_as_uint(best);
        sv = (sv & 0x80000000u) ? ~sv : (sv | 0x80000000u);
        unsigned long long p = ((unsigned long long)sv << 32)
                             | (unsigned long long)(0xFFFFFFFFu - (unsigned)bi);
        atomicMax(packed + b * NLOC + m0 + tid, p);
    }
}

// ---------------- finalize ----------------
__global__ __launch_bounds__(256) void finalize_kernel(const unsigned long long* __restrict__ packed,
                                                       const float* __restrict__ nl_inv,
                                                       float* __restrict__ S,
                                                       int* __restrict__ Rarg)
{
    int i = blockIdx.x * 256 + threadIdx.x;
    if (i >= BATCH * NLOC) return;
    unsigned long long p = packed[i];
    unsigned int sv   = (unsigned int)(p >> 32);
    unsigned int bits = (sv & 0x80000000u) ? (sv & 0x7FFFFFFFu) : ~sv;
    S[i]    = __uint_as_float(bits) * nl_inv[i];
    Rarg[i] = (int)(0xFFFFFFFFu - (unsigned int)(p & 0xFFFFFFFFu));
}

// ---------------- transfer lv1: S=4, K=12, P=4, C=64, H=192 — float4 cells ----------------
__global__ __launch_bounds__(256) void transfer1_kernel(const float* __restrict__ ref,
                                                        const int* __restrict__ Rarg,
                                                        float* __restrict__ out)
{
    int idx = blockIdx.x * 256 + threadIdx.x;        // 4*64*192*48
    int cx = idx % 48;
    int y  = (idx / 48) % 192;
    int c  = (idx / (48 * 192)) & 63;
    int b  = idx / (48 * 192 * 64);
    int x0 = cx * 4;
    int Y = y + 4, X0 = x0 + 4;
    int ylo = (Y >= 12) ? (Y - 8) >> 2 : 0;
    int yhi = Y >> 2; if (yhi > 47) yhi = 47;
    int xlo = (X0 >= 12) ? (X0 - 8) >> 2 : 0;
    int xhi = X0 >> 2; if (xhi > 47) xhi = 47;
    const float* rb = ref + (size_t)(b * 64 + c) * 192 * 192;
    const int*   ab = Rarg + b * NLOC;
    float4 acc = make_float4(0.f, 0.f, 0.f, 0.f);
    for (int py = ylo; py <= yhi; ++py) {
        int rowk = Y - 4 * py - 4;
        for (int px = xlo; px <= xhi; ++px) {
            unsigned q = (unsigned)ab[py * 48 + px];
            int qy = q / 48u, qx = q % 48u;
            int row = qy * 4 + rowk;
            int col = qx * 4 + (X0 - 4 * px - 4);
            if ((unsigned)row < 192u && (unsigned)col < 192u) {
                float4 v = *(const float4*)(rb + row * 192 + col);
                acc.x += v.x; acc.y += v.y; acc.z += v.z; acc.w += v.w;
            }
        }
    }
    const float s = 1.f / 9.f;
    acc.x *= s; acc.y *= s; acc.z *= s; acc.w *= s;
    *(float4*)(out + (size_t)idx * 4) = acc;
}

// ---------------- transfer lv2: S=2, K=6, P=2, C=128, H=96 — float2 cells ----------------
__global__ __launch_bounds__(256) void transfer2_kernel(const float* __restrict__ ref,
                                                        const int* __restrict__ Rarg,
                                                        float* __restrict__ out)
{
    int idx = blockIdx.x * 256 + threadIdx.x;        // 4*128*96*48
    int cx = idx % 48;
    int y  = (idx / 48) % 96;
    int c  = (idx / (48 * 96)) & 127;
    int b  = idx / (48 * 96 * 128);
    int x0 = cx * 2;
    int Y = y + 2, X0 = x0 + 2;
    int ylo = (Y >= 6) ? (Y - 4) >> 1 : 0;
    int yhi = Y >> 1; if (yhi > 47) yhi = 47;
    int xlo = (X0 >= 6) ? (X0 - 4) >> 1 : 0;
    int xhi = X0 >> 1; if (xhi > 47) xhi = 47;
    const float* rb = ref + (size_t)(b * 128 + c) * 96 * 96;
    const int*   ab = Rarg + b * NLOC;
    float2 acc = make_float2(0.f, 0.f);
    for (int py = ylo; py <= yhi; ++py) {
        int rowk = Y - 2 * py - 2;
        for (int px = xlo; px <= xhi; ++px) {
            unsigned q = (unsigned)ab[py * 48 + px];
            int qy = q / 48u, qx = q % 48u;
            int row = qy * 2 + rowk;
            int col = qx * 2 + (X0 - 2 * px - 2);
            if ((unsigned)row < 96u && (unsigned)col < 96u) {
                float2 v = *(const float2*)(rb + row * 96 + col);
                acc.x += v.x; acc.y += v.y;
            }
        }
    }
    const float s = 1.f / 9.f;
    acc.x *= s; acc.y *= s;
    *(float2*)(out + (size_t)idx * 2) = acc;
}

// ---------------- transfer lv3: S=1, K=3, P=1, C=256, H=48 — scalar ----------------
__global__ __launch_bounds__(256) void transfer3_kernel(const float* __restrict__ ref,
                                                        const int* __restrict__ Rarg,
                                                        float* __restrict__ out)
{
    int idx = blockIdx.x * 256 + threadIdx.x;        // 4*256*48*48
    int x = idx % 48;
    int y = (idx / 48) % 48;
    int c = (idx / NLOC) & 255;
    int b = idx / (NLOC * 256);
    int Y = y + 1, X = x + 1;
    int ylo = Y - 2; if (ylo < 0) ylo = 0;
    int yhi = Y; if (yhi > 47) yhi = 47;
    int xlo = X - 2; if (xlo < 0) xlo = 0;
    int xhi = X; if (xhi > 47) xhi = 47;
    const float* rb = ref + (size_t)(b * 256 + c) * NLOC;
    const int*   ab = Rarg + b * NLOC;
    float acc = 0.f;
    for (int py = ylo; py <= yhi; ++py) {
        int rowk = Y - py - 1;
        for (int px = xlo; px <= xhi; ++px) {
            unsigned q = (unsigned)ab[py * 48 + px];
            int qy = q / 48u, qx = q % 48u;
            int row = qy + rowk;
            int col = qx + (X - px) - 1;
            if ((unsigned)row < 48u && (unsigned)col < 48u)
                acc += rb[row * 48 + col];
        }
    }
    out[idx] = acc * (1.f / 9.f);
}

extern "C" void kernel_launch(void* const* d_in, const int* in_sizes, int n_in,
                              void* d_out, int out_size, void* d_ws, size_t ws_size,
                              hipStream_t stream)
{
    const float* lrsr  = (const float*)d_in[0];
    const float* refsr = (const float*)d_in[1];
    const float* ref1  = (const float*)d_in[2];
    const float* ref2  = (const float*)d_in[3];
    const float* ref3  = (const float*)d_in[4];

    float* S_out  = (float*)d_out;
    float* T3_out = S_out  + BATCH * NLOC;
    float* T2_out = T3_out + BATCH * 256 * 48 * 48;
    float* T1_out = T2_out + BATCH * 128 * 96 * 96;

    char* ws = (char*)d_ws;
    unsigned long long* packed = (unsigned long long*)ws;     // 73728 B
    float* nr_inv = (float*)(ws + 73728);
    float* nl_inv = (float*)(ws + 110592);
    int*   Rarg   = (int*)(ws + 147456);
    float* ss_r   = (float*)(ws + 184320);
    float* ss_l   = (float*)(ws + 221184);
    const size_t PLANE = (size_t)BATCH * NLOC50 * 256;        // 2,560,000 halves = 5,120,000 B
    unsigned short* A_hi = (unsigned short*)(ws + 258048);
    unsigned short* A_lo = A_hi + PLANE;
    unsigned short* B_hi = A_lo + PLANE;
    unsigned short* B_lo = B_hi + PLANE;

    // zero packed + plane borders in one shot
    hipMemsetAsync(ws, 0, 258048 + 4 * PLANE * sizeof(unsigned short), stream);

    ss_kernel<<<dim3(36), 256, 0, stream>>>(refsr, ss_r);
    ss_kernel<<<dim3(36), 256, 0, stream>>>(lrsr,  ss_l);
    prep_kernel<<<dim3(192), 256, 0, stream>>>(refsr, A_hi, A_lo);
    prep_kernel<<<dim3(192), 256, 0, stream>>>(lrsr,  B_hi, B_lo);
    normS_kernel<<<dim3(36), 256, 0, stream>>>(ss_r, nr_inv);
    normS_kernel<<<dim3(36), 256, 0, stream>>>(ss_l, nl_inv);

    search_mfma<<<dim3(36, 9, BATCH), 256, 0, stream>>>(A_hi, A_lo, B_hi, B_lo, nr_inv, packed);

    finalize_kernel<<<dim3(36), 256, 0, stream>>>(packed, nl_inv, S_out, Rarg);

    transfer3_kernel<<<dim3(BATCH * 256 * 48 * 48 / 256), 256, 0, stream>>>(ref3, Rarg, T3_out);
    transfer2_kernel<<<dim3(BATCH * 128 * 96 * 48 / 256), 256, 0, stream>>>(ref2, Rarg, T2_out);
    transfer1_kernel<<<dim3(BATCH * 64 * 192 * 48 / 256), 256, 0, stream>>>(ref1, Rarg, T1_out);
}